// Round 2
// baseline (732.738 us; speedup 1.0000x reference)
//
#include <hip/hip_runtime.h>

typedef float f32x4 __attribute__((ext_vector_type(4)));
typedef __bf16 bf16x8 __attribute__((ext_vector_type(8)));
typedef short s16x8 __attribute__((ext_vector_type(8)));
typedef unsigned short u16;

#define DEV static __device__ __forceinline__

constexpr int BATCH = 4;
constexpr int SQ    = 2048;
constexpr int SKV   = 2048;
constexpr int DMODEL= 512;
constexpr int NH    = 8;
constexpr int DH    = 64;
constexpr int MROWS = BATCH * SQ;      // 8192 (same for x and y)
constexpr float LN_EPS = 1e-5f;

DEV u16 f2bf(float f) {
    unsigned u = __builtin_bit_cast(unsigned, f);
    unsigned r = (u + 0x7FFFu + ((u >> 16) & 1u)) >> 16;
    return (u16)r;
}
DEV float bf2f(u16 h) { return __builtin_bit_cast(float, ((unsigned)h) << 16); }

DEV f32x4 mfma16(s16x8 a, s16x8 b, f32x4 c) {
    return __builtin_amdgcn_mfma_f32_16x16x32_bf16(
        __builtin_bit_cast(bf16x8, a), __builtin_bit_cast(bf16x8, b), c, 0, 0, 0);
}

// ---------------------------------------------------------------------------
// LayerNorm + split to bf16 hi/lo. One wave per row of 512. Block = 4 rows.
// ---------------------------------------------------------------------------
__global__ __launch_bounds__(256) void ln_split_kernel(
    const float* __restrict__ X, const float* __restrict__ G, const float* __restrict__ Bt,
    u16* __restrict__ oh, u16* __restrict__ ol)
{
    int row  = blockIdx.x * 4 + (threadIdx.x >> 6);
    int lane = threadIdx.x & 63;
    const float4* xr = (const float4*)(X + (size_t)row * DMODEL);
    float4 a = xr[lane * 2], b = xr[lane * 2 + 1];
    float vv[8] = {a.x, a.y, a.z, a.w, b.x, b.y, b.z, b.w};
    float s = 0.f;
#pragma unroll
    for (int i = 0; i < 8; i++) s += vv[i];
#pragma unroll
    for (int o = 32; o; o >>= 1) s += __shfl_xor(s, o);
    float mu = s * (1.0f / DMODEL);
    float vs = 0.f;
#pragma unroll
    for (int i = 0; i < 8; i++) { float d = vv[i] - mu; vs += d * d; }
#pragma unroll
    for (int o = 32; o; o >>= 1) vs += __shfl_xor(vs, o);
    float rstd = rsqrtf(vs * (1.0f / DMODEL) + LN_EPS);

    const float4* g4 = (const float4*)G;
    const float4* b4 = (const float4*)Bt;
    float4 g0 = g4[lane * 2], g1 = g4[lane * 2 + 1];
    float4 c0 = b4[lane * 2], c1 = b4[lane * 2 + 1];
    float gg[8] = {g0.x, g0.y, g0.z, g0.w, g1.x, g1.y, g1.z, g1.w};
    float cc[8] = {c0.x, c0.y, c0.z, c0.w, c1.x, c1.y, c1.z, c1.w};

    s16x8 vh, vl;
#pragma unroll
    for (int i = 0; i < 8; i++) {
        float t = (vv[i] - mu) * rstd * gg[i] + cc[i];
        u16 h = f2bf(t);
        vh[i] = (short)h;
        vl[i] = (short)f2bf(t - bf2f(h));
    }
    size_t o0 = (size_t)row * DMODEL + lane * 8;
    *(s16x8*)(oh + o0) = vh;
    *(s16x8*)(ol + o0) = vl;
}

// ---------------------------------------------------------------------------
// Weight transpose + split: W [K=512][N=512] row-major -> WT_hi/lo [N][K]
// ---------------------------------------------------------------------------
__global__ __launch_bounds__(256) void wsplit_kernel(
    const float* __restrict__ W, u16* __restrict__ th, u16* __restrict__ tl)
{
    int idx = blockIdx.x * 256 + threadIdx.x;  // idx = n*512 + k
    int n = idx >> 9, k = idx & 511;
    float v = W[(size_t)k * 512 + n];
    u16 h = f2bf(v);
    th[idx] = h;
    tl[idx] = f2bf(v - bf2f(h));
}

// ---------------------------------------------------------------------------
// Split-bf16 GEMM: C[M=8192][N=512] = A[M][K=512] * B^T (B stored [N][K]),
// 3-term (hi*hi + hi*lo + lo*hi). 64x64 tile, 4 waves (2x2), BK=64.
// MODE 0: Q/K -> hi/lo at (b,h,s,d), scaled by scl
// MODE 1: V   -> bf16 at (b,h,d,s)   (V^T)
// MODE 2: out -> fp32 [M][512] + bias
// ---------------------------------------------------------------------------
template<int MODE>
__global__ __launch_bounds__(256) void gemm_split(
    const u16* __restrict__ Ah, const u16* __restrict__ Al,
    const u16* __restrict__ Bh, const u16* __restrict__ Bl,
    void* __restrict__ out0, void* __restrict__ out1,
    const float* __restrict__ bias, float scl)
{
    constexpr int K  = 512;
    constexpr int LS = 72;   // padded LDS row stride (bf16 elems)
    __shared__ u16 lA[2][64][LS];
    __shared__ u16 lB[2][64][LS];

    int bm = blockIdx.x, bn = blockIdx.y;
    int tid = threadIdx.x, lane = tid & 63, wv = tid >> 6;
    int wm = (wv >> 1) * 32, wn = (wv & 1) * 32;
    // staging: row = (tid>>3) + p*32 (p=0,1), col = (tid&7)*8 -> full 64x64 tile
    int srow = tid >> 3, scol = (tid & 7) * 8;
    const size_t aoff0 = ((size_t)(bm * 64 + srow)) * K + scol;
    const size_t aoff1 = ((size_t)(bm * 64 + srow + 32)) * K + scol;
    const size_t boff0 = ((size_t)(bn * 64 + srow)) * K + scol;
    const size_t boff1 = ((size_t)(bn * 64 + srow + 32)) * K + scol;

    f32x4 acc[2][2] = {};

    for (int k0 = 0; k0 < K; k0 += 64) {
        *(int4*)&lA[0][srow][scol]      = *(const int4*)(Ah + aoff0 + k0);
        *(int4*)&lA[0][srow + 32][scol] = *(const int4*)(Ah + aoff1 + k0);
        *(int4*)&lA[1][srow][scol]      = *(const int4*)(Al + aoff0 + k0);
        *(int4*)&lA[1][srow + 32][scol] = *(const int4*)(Al + aoff1 + k0);
        *(int4*)&lB[0][srow][scol]      = *(const int4*)(Bh + boff0 + k0);
        *(int4*)&lB[0][srow + 32][scol] = *(const int4*)(Bh + boff1 + k0);
        *(int4*)&lB[1][srow][scol]      = *(const int4*)(Bl + boff0 + k0);
        *(int4*)&lB[1][srow + 32][scol] = *(const int4*)(Bl + boff1 + k0);
        __syncthreads();
        int fr = lane & 15, fg = (lane >> 4) * 8;
#pragma unroll
        for (int kk = 0; kk < 64; kk += 32) {
            s16x8 ah[2], al[2], bh[2], bl[2];
#pragma unroll
            for (int m_ = 0; m_ < 2; m_++) {
                ah[m_] = *(const s16x8*)&lA[0][wm + m_ * 16 + fr][kk + fg];
                al[m_] = *(const s16x8*)&lA[1][wm + m_ * 16 + fr][kk + fg];
            }
#pragma unroll
            for (int n_ = 0; n_ < 2; n_++) {
                bh[n_] = *(const s16x8*)&lB[0][wn + n_ * 16 + fr][kk + fg];
                bl[n_] = *(const s16x8*)&lB[1][wn + n_ * 16 + fr][kk + fg];
            }
#pragma unroll
            for (int m_ = 0; m_ < 2; m_++)
#pragma unroll
                for (int n_ = 0; n_ < 2; n_++) {
                    acc[m_][n_] = mfma16(ah[m_], bh[n_], acc[m_][n_]);
                    acc[m_][n_] = mfma16(ah[m_], bl[n_], acc[m_][n_]);
                    acc[m_][n_] = mfma16(al[m_], bh[n_], acc[m_][n_]);
                }
        }
        __syncthreads();
    }

    int fr = lane & 15, fq = lane >> 4;
#pragma unroll
    for (int m_ = 0; m_ < 2; m_++)
#pragma unroll
        for (int n_ = 0; n_ < 2; n_++)
#pragma unroll
            for (int r = 0; r < 4; r++) {
                int gm = bm * 64 + wm + m_ * 16 + fq * 4 + r;
                int gn = bn * 64 + wn + n_ * 16 + fr;
                float v = acc[m_][n_][r];
                if (MODE == 0) {
                    v *= scl;
                    int b_ = gm >> 11, s_ = gm & 2047, h_ = gn >> 6, d_ = gn & 63;
                    size_t adr = (((size_t)(b_ * NH + h_)) * SKV + s_) * DH + d_;
                    u16 hv = f2bf(v);
                    ((u16*)out0)[adr] = hv;
                    ((u16*)out1)[adr] = f2bf(v - bf2f(hv));
                } else if (MODE == 1) {
                    int b_ = gm >> 11, s_ = gm & 2047, h_ = gn >> 6, d_ = gn & 63;
                    size_t adr = (((size_t)(b_ * NH + h_)) * DH + d_) * SKV + s_;
                    ((u16*)out0)[adr] = f2bf(v);
                } else {
                    v += bias[gn];
                    ((float*)out0)[(size_t)gm * DMODEL + gn] = v;
                }
            }
}

// ---------------------------------------------------------------------------
// Fused attention: one block per (b,h, 16-row q tile). 8 waves.
// S[16][2048] fp32 in LDS (stride 2052). Split-bf16 QK^T (fp32-accurate),
// wave-parallel softmax stats, attn written once, PV bf16 MFMA.
// ---------------------------------------------------------------------------
constexpr int SROW = 2052;

__global__ __launch_bounds__(512) void attn_kernel(
    const u16* __restrict__ Qh, const u16* __restrict__ Ql,
    const u16* __restrict__ Kh, const u16* __restrict__ Kl,
    const u16* __restrict__ VT,
    float* __restrict__ attn, u16* __restrict__ ch, u16* __restrict__ cl)
{
    __shared__ float S[16 * SROW + 16];   // + 16 floats of inv_l
    int tid = threadIdx.x, lane = tid & 63, w = tid >> 6;
    int qt = blockIdx.x & 127, bh = blockIdx.x >> 7;
    const size_t base = (size_t)bh * (SKV * DH);
    int fr = lane & 15, fg = lane >> 4;

    // Q fragments (rows qt*16 .. +15, all 64 d), hi and lo
    const u16* qp  = Qh + base + ((size_t)(qt * 16 + fr)) * DH + fg * 8;
    const u16* qlp = Ql + base + ((size_t)(qt * 16 + fr)) * DH + fg * 8;
    s16x8 q_h0 = *(const s16x8*)qp,  q_h1 = *(const s16x8*)(qp + 32);
    s16x8 q_l0 = *(const s16x8*)qlp, q_l1 = *(const s16x8*)(qlp + 32);

    int kv0 = w * 256;
    // ---- S = (Q*scale) K^T, split 3-term (lo*hi term uses Ql) ----
#pragma unroll 4
    for (int n = 0; n < 16; n++) {
        const u16* kp  = Kh + base + ((size_t)(kv0 + n * 16 + fr)) * DH + fg * 8;
        const u16* klp = Kl + base + ((size_t)(kv0 + n * 16 + fr)) * DH + fg * 8;
        s16x8 k_h0 = *(const s16x8*)kp,  k_h1 = *(const s16x8*)(kp + 32);
        s16x8 k_l0 = *(const s16x8*)klp, k_l1 = *(const s16x8*)(klp + 32);
        f32x4 a = {};
        a = mfma16(q_h0, k_h0, a);
        a = mfma16(q_h1, k_h1, a);
        a = mfma16(q_h0, k_l0, a);
        a = mfma16(q_h1, k_l1, a);
        a = mfma16(q_l0, k_h0, a);
        a = mfma16(q_l1, k_h1, a);
#pragma unroll
        for (int r = 0; r < 4; r++)
            S[(fg * 4 + r) * SROW + kv0 + n * 16 + fr] = a[r];
    }
    __syncthreads();

    // ---- softmax stats: wave w handles rows 2w, 2w+1; in-place exp ----
#pragma unroll
    for (int rr = 0; rr < 2; rr++) {
        int r = w * 2 + rr;
        float* Sr = &S[r * SROW];
        float mx = -1e30f;
#pragma unroll
        for (int i = 0; i < 32; i++) mx = fmaxf(mx, Sr[lane + 64 * i]);
#pragma unroll
        for (int o = 32; o; o >>= 1) mx = fmaxf(mx, __shfl_xor(mx, o));
        float sm = 0.f;
#pragma unroll
        for (int i = 0; i < 32; i++) {
            float e = __expf(Sr[lane + 64 * i] - mx);
            Sr[lane + 64 * i] = e;
            sm += e;
        }
#pragma unroll
        for (int o = 32; o; o >>= 1) sm += __shfl_xor(sm, o);
        if (lane == 0) S[16 * SROW + r] = 1.0f / sm;
    }
    __syncthreads();

    // ---- write attn = E * inv_l (coalesced float4) ----
    {
        size_t ab = ((size_t)bh * SQ + qt * 16) * SKV;
#pragma unroll 4
        for (int r = 0; r < 16; r++) {
            float il = S[16 * SROW + r];
            float4 vv = *(const float4*)&S[r * SROW + tid * 4];
            float4 o;
            o.x = vv.x * il; o.y = vv.y * il; o.z = vv.z * il; o.w = vv.w * il;
            *(float4*)&attn[ab + (size_t)r * SKV + tid * 4] = o;
        }
    }

    // ---- PV: wave w covers kv slice [kv0, kv0+256) ----
    f32x4 pacc[4] = {};
    const u16* vb = VT + (size_t)bh * (DH * SKV);
#pragma unroll 2
    for (int kt = 0; kt < 8; kt++) {
        const float* ep = &S[fr * SROW + kv0 + kt * 32 + fg * 8];
        float4 e0 = *(const float4*)ep, e1 = *(const float4*)(ep + 4);
        s16x8 pa;
        pa[0] = (short)f2bf(e0.x); pa[1] = (short)f2bf(e0.y);
        pa[2] = (short)f2bf(e0.z); pa[3] = (short)f2bf(e0.w);
        pa[4] = (short)f2bf(e1.x); pa[5] = (short)f2bf(e1.y);
        pa[6] = (short)f2bf(e1.z); pa[7] = (short)f2bf(e1.w);
#pragma unroll
        for (int n = 0; n < 4; n++) {
            const u16* vp = vb + ((size_t)(n * 16 + fr)) * SKV + kv0 + kt * 32 + fg * 8;
            s16x8 vv = *(const s16x8*)vp;
            pacc[n] = mfma16(pa, vv, pacc[n]);
        }
    }
    __syncthreads();   // everyone done reading S (attn write + PV)

    // ---- cross-wave reduce of PV partials (reuse S area) ----
#pragma unroll
    for (int n = 0; n < 4; n++)
#pragma unroll
        for (int r = 0; r < 4; r++)
            S[w * 1024 + (fg * 4 + r) * 64 + n * 16 + fr] = pacc[n][r];
    __syncthreads();

    {
        int b_ = bh >> 3, h_ = bh & 7;
#pragma unroll
        for (int j = 0; j < 2; j++) {
            int idx = tid * 2 + j;
            int q = idx >> 6, dv = idx & 63;
            float sum = 0.f;
#pragma unroll
            for (int w2 = 0; w2 < 8; w2++) sum += S[w2 * 1024 + idx];
            sum *= S[16 * SROW + q];
            size_t adr = ((size_t)(b_ * SQ) + qt * 16 + q) * DMODEL + h_ * 64 + dv;
            u16 hv = f2bf(sum);
            ch[adr] = hv;
            cl[adr] = f2bf(sum - bf2f(hv));
        }
    }
}

// ---------------------------------------------------------------------------
extern "C" void kernel_launch(void* const* d_in, const int* in_sizes, int n_in,
                              void* d_out, int out_size, void* d_ws, size_t ws_size,
                              hipStream_t stream)
{
    const float* x   = (const float*)d_in[0];
    const float* y   = (const float*)d_in[1];
    const float* lqg = (const float*)d_in[2];
    const float* lqb = (const float*)d_in[3];
    const float* lkg = (const float*)d_in[4];
    const float* lkb = (const float*)d_in[5];
    const float* Wq  = (const float*)d_in[6];
    const float* Wk  = (const float*)d_in[7];
    const float* Wv  = (const float*)d_in[8];
    const float* Wo  = (const float*)d_in[9];
    const float* bo  = (const float*)d_in[10];

    char* ws = (char*)d_ws;
    size_t off = 0;
    auto alloc = [&](size_t nelem) -> u16* {
        u16* p = (u16*)(ws + off);
        off += (nelem * 2 + 255) & ~(size_t)255;
        return p;
    };
    const size_t NROW = (size_t)MROWS * DMODEL;   // 8192*512
    u16* xnh = alloc(NROW);  u16* xnl = alloc(NROW);
    u16* ynh = alloc(NROW);  u16* ynl = alloc(NROW);
    u16* wqh = alloc(512 * 512); u16* wql = alloc(512 * 512);
    u16* wkh = alloc(512 * 512); u16* wkl = alloc(512 * 512);
    u16* wvh = alloc(512 * 512); u16* wvl = alloc(512 * 512);
    u16* woh = alloc(512 * 512); u16* wol = alloc(512 * 512);
    u16* qh_ = alloc(NROW);  u16* ql_ = alloc(NROW);
    u16* kh_ = alloc(NROW);  u16* kl_ = alloc(NROW);
    u16* vt_ = alloc(NROW);
    u16* cth = alloc(NROW);  u16* ctl = alloc(NROW);

    float* outp  = (float*)d_out;
    float* attnp = outp + (size_t)MROWS * DMODEL;   // after (B,SQ,512) out

    ln_split_kernel<<<MROWS / 4, 256, 0, stream>>>(x, lqg, lqb, xnh, xnl);
    ln_split_kernel<<<MROWS / 4, 256, 0, stream>>>(y, lkg, lkb, ynh, ynl);
    wsplit_kernel<<<1024, 256, 0, stream>>>(Wq, wqh, wql);
    wsplit_kernel<<<1024, 256, 0, stream>>>(Wk, wkh, wkl);
    wsplit_kernel<<<1024, 256, 0, stream>>>(Wv, wvh, wvl);
    wsplit_kernel<<<1024, 256, 0, stream>>>(Wo, woh, wol);

    dim3 gg(MROWS / 64, 512 / 64);
    gemm_split<0><<<gg, 256, 0, stream>>>(xnh, xnl, wqh, wql, qh_, ql_, nullptr, 0.125f);
    gemm_split<0><<<gg, 256, 0, stream>>>(ynh, ynl, wkh, wkl, kh_, kl_, nullptr, 1.0f);
    gemm_split<1><<<gg, 256, 0, stream>>>(ynh, ynl, wvh, wvl, vt_, nullptr, nullptr, 1.0f);

    attn_kernel<<<BATCH * NH * (SQ / 16), 512, 0, stream>>>(qh_, ql_, kh_, kl_, vt_,
                                                            attnp, cth, ctl);

    gemm_split<2><<<gg, 256, 0, stream>>>(cth, ctl, woh, wol, (void*)outp, nullptr, bo, 1.0f);
}